// Round 7
// baseline (164.325 us; speedup 1.0000x reference)
//
#include <hip/hip_runtime.h>
#include <math.h>

#define IMG 512
#define TW 128     // output tile width
#define TH 16      // output tile height
#define RS 150     // LDS row stride floats: 150%32=22, gcd(22,32)=2 -> 16 rows cover all
                   // 16 even bank residues exactly once (h-read conflict killer, round 5)
#define NQ 36      // col-quads per intermediate row (cols x0-8 .. x0+135; halo = 2 full quads/side)
#define BT 576     // block threads = 16*36 v-tasks, exactly one per thread (round-7:
                   // kills the wave-0 double-task that made the v-phase critical path 2x)
#define MMB 1024   // minmax stage-1 blocks

struct W11 { float w[11]; };

__device__ __forceinline__ unsigned omap(float f) {
  unsigned b = __float_as_uint(f);
  return (b & 0x80000000u) ? ~b : (b | 0x80000000u);
}
__device__ __forceinline__ float ounmap(unsigned u) {
  return __uint_as_float((u & 0x80000000u) ? (u ^ 0x80000000u) : ~u);
}

// Stage 1: per-block partial min/max -> disjoint slots, no atomics.
__global__ __launch_bounds__(256) void minmax_part(const float4* __restrict__ img,
                                                   int n4, unsigned* __restrict__ part) {
  unsigned mx = 0u, mn = 0xFFFFFFFFu;
  int stride = gridDim.x * blockDim.x;
  for (int i = blockIdx.x * blockDim.x + threadIdx.x; i < n4; i += stride) {
    float4 v = img[i];
    unsigned a = omap(v.x), b = omap(v.y), c = omap(v.z), d = omap(v.w);
    mx = max(mx, max(max(a, b), max(c, d)));
    mn = min(mn, min(min(a, b), min(c, d)));
  }
  #pragma unroll
  for (int off = 32; off > 0; off >>= 1) {
    mx = max(mx, __shfl_down(mx, off));
    mn = min(mn, __shfl_down(mn, off));
  }
  __shared__ unsigned smx[4], smn[4];
  int lane = threadIdx.x & 63, wv = threadIdx.x >> 6;
  if (lane == 0) { smx[wv] = mx; smn[wv] = mn; }
  __syncthreads();
  if (threadIdx.x == 0) {
    mx = max(max(smx[0], smx[1]), max(smx[2], smx[3]));
    mn = min(min(smn[0], smn[1]), min(smn[2], smn[3]));
    part[2 * blockIdx.x]     = mx;
    part[2 * blockIdx.x + 1] = mn;
  }
}

// Stage 2: fold MMB partial pairs into ws[0]=max, ws[1]=min.
__global__ __launch_bounds__(256) void minmax_final(const unsigned* __restrict__ part,
                                                    unsigned* __restrict__ ws) {
  unsigned mx = 0u, mn = 0xFFFFFFFFu;
  for (int i = threadIdx.x; i < MMB; i += 256) {
    mx = max(mx, part[2 * i]);
    mn = min(mn, part[2 * i + 1]);
  }
  #pragma unroll
  for (int off = 32; off > 0; off >>= 1) {
    mx = max(mx, __shfl_down(mx, off));
    mn = min(mn, __shfl_down(mn, off));
  }
  __shared__ unsigned smx[4], smn[4];
  int lane = threadIdx.x & 63, wv = threadIdx.x >> 6;
  if (lane == 0) { smx[wv] = mx; smn[wv] = mn; }
  __syncthreads();
  if (threadIdx.x == 0) {
    ws[0] = max(max(smx[0], smx[1]), max(smx[2], smx[3]));
    ws[1] = min(min(smn[0], smn[1]), min(smn[2], smn[3]));
  }
}

// One vertical task: 11-tap v-conv of {a, b, a^2+b^2, a*b} for (1 row x 4 cols).
// Loads written as named float4 registers; note (round-6 finding): the
// occupancy-maximizing scheduler sinks these back to ~3-6 in flight to stay
// <=64 VGPR / 8 waves per EU. Kept because it's harmless and documents intent.
__device__ __forceinline__ void vtask(int t, int x0, int y0, bool y_full,
                                      const float* __restrict__ p1,
                                      const float* __restrict__ p2,
                                      const W11& wv,
                                      float (*V)[TH][RS]) {
  const int r = t / NQ;              // 0..15
  const int q = t - r * NQ;          // 0..35
  const int gx0 = x0 - 8 + 4 * q;    // multiple of 4; halo quads are fully OOB
  const int gy0 = y0 + r - 5;

  float4 a0, a1, a2, a3, a4, a5, a6, a7, a8, a9, a10;
  float4 b0, b1, b2, b3, b4, b5, b6, b7, b8, b9, b10;

#define ZROW(ak, bk) { ak = make_float4(0.f, 0.f, 0.f, 0.f); bk = make_float4(0.f, 0.f, 0.f, 0.f); }
#define FROW(k, ak, bk) { ak = A[(k) * (IMG / 4)]; bk = B[(k) * (IMG / 4)]; }
#define GROW(k, ak, bk) { int row = gy0 + (k);                                \
    if ((unsigned)row < IMG) {                                                \
      ak = *(const float4*)(p1 + (size_t)row * IMG + gx0);                    \
      bk = *(const float4*)(p2 + (size_t)row * IMG + gx0);                    \
    } else ZROW(ak, bk) }

  if ((unsigned)gx0 < IMG) {
    if (y_full) {
      const float4* A = (const float4*)(p1 + (size_t)gy0 * IMG + gx0);
      const float4* B = (const float4*)(p2 + (size_t)gy0 * IMG + gx0);
      FROW(0, a0, b0)  FROW(1, a1, b1)  FROW(2, a2, b2)  FROW(3, a3, b3)
      FROW(4, a4, b4)  FROW(5, a5, b5)  FROW(6, a6, b6)  FROW(7, a7, b7)
      FROW(8, a8, b8)  FROW(9, a9, b9)  FROW(10, a10, b10)
    } else {
      GROW(0, a0, b0)  GROW(1, a1, b1)  GROW(2, a2, b2)  GROW(3, a3, b3)
      GROW(4, a4, b4)  GROW(5, a5, b5)  GROW(6, a6, b6)  GROW(7, a7, b7)
      GROW(8, a8, b8)  GROW(9, a9, b9)  GROW(10, a10, b10)
    }
  } else {
    ZROW(a0, b0)  ZROW(a1, b1)  ZROW(a2, b2)  ZROW(a3, b3)  ZROW(a4, b4)
    ZROW(a5, b5)  ZROW(a6, b6)  ZROW(a7, b7)  ZROW(a8, b8)  ZROW(a9, b9)
    ZROW(a10, b10)
  }
#undef ZROW
#undef FROW
#undef GROW

  float c0x = 0.f, c0y = 0.f, c0z = 0.f, c0w = 0.f;   // mu1
  float c1x = 0.f, c1y = 0.f, c1z = 0.f, c1w = 0.f;   // mu2
  float c2x = 0.f, c2y = 0.f, c2z = 0.f, c2w = 0.f;   // a^2+b^2
  float c3x = 0.f, c3y = 0.f, c3z = 0.f, c3w = 0.f;   // a*b

#define VSTEP(k, a, b)                                                        \
  {                                                                           \
    float wk = wv.w[k];                                                       \
    c0x += wk * a.x; c0y += wk * a.y; c0z += wk * a.z; c0w += wk * a.w;       \
    c1x += wk * b.x; c1y += wk * b.y; c1z += wk * b.z; c1w += wk * b.w;       \
    float sx = a.x * a.x + b.x * b.x, sy = a.y * a.y + b.y * b.y;             \
    float sz = a.z * a.z + b.z * b.z, sw = a.w * a.w + b.w * b.w;             \
    c2x += wk * sx; c2y += wk * sy; c2z += wk * sz; c2w += wk * sw;           \
    float px = a.x * b.x, py = a.y * b.y, pz = a.z * b.z, pw = a.w * b.w;     \
    c3x += wk * px; c3y += wk * py; c3z += wk * pz; c3w += wk * pw;           \
  }

  VSTEP(0, a0, b0)   VSTEP(1, a1, b1)   VSTEP(2, a2, b2)   VSTEP(3, a3, b3)
  VSTEP(4, a4, b4)   VSTEP(5, a5, b5)   VSTEP(6, a6, b6)   VSTEP(7, a7, b7)
  VSTEP(8, a8, b8)   VSTEP(9, a9, b9)   VSTEP(10, a10, b10)
#undef VSTEP

  // b64 writes, consecutive lanes -> consecutive addresses (clean class).
  // Stores end accumulator liveness.
  *(float2*)&V[0][r][4 * q]     = make_float2(c0x, c0y);
  *(float2*)&V[0][r][4 * q + 2] = make_float2(c0z, c0w);
  *(float2*)&V[1][r][4 * q]     = make_float2(c1x, c1y);
  *(float2*)&V[1][r][4 * q + 2] = make_float2(c1z, c1w);
  *(float2*)&V[2][r][4 * q]     = make_float2(c2x, c2y);
  *(float2*)&V[2][r][4 * q + 2] = make_float2(c2z, c2w);
  *(float2*)&V[3][r][4 * q]     = make_float2(c3x, c3y);
  *(float2*)&V[3][r][4 * q + 2] = make_float2(c3z, c3w);
}

// Fused SSIM, v-first, b64-only LDS, conflict-minimized.
// Round-7: 576-thread block = exactly one v-task per thread. Rounds 4-6 had
// wave 0 doing TWO tasks while 7 waves waited at the barrier -> v-phase
// critical path was 2 tasks for every block. Now 1. Cost: 9-wave blocks ->
// 3 blocks/CU (27 waves vs 32), a good trade if latency-bound (round-5/6
// profile: all pipes <=50%).
// launch_bounds(576,3): no meaningful VGPR cap; compiler lands at its natural
// ~56-64 VGPR / spill-free regime (verified rounds 4-6).
__global__ __launch_bounds__(BT, 3) void ssim_k(const float* __restrict__ img1,
                                                const float* __restrict__ img2,
                                                float* __restrict__ out,
                                                const unsigned* __restrict__ ws,
                                                W11 wv) {
  __shared__ float V[4][TH][RS];   // 38400 B

  const int tid = threadIdx.x;
  const int bx = blockIdx.x, by = blockIdx.y, n = blockIdx.z;
  const float* p1 = img1 + (size_t)n * IMG * IMG;
  const float* p2 = img2 + (size_t)n * IMG * IMG;
  const int x0 = bx * TW;
  const int y0 = by * TH;

  // C1/C2 (scalar loads issued early; needed after the barrier)
  float L = ounmap(ws[0]) - ounmap(ws[1]);
  if (L == 0.f) L = 5.f;
  float C1 = 0.01f * L; C1 *= C1;
  float C2 = 0.03f * L; C2 *= C2;

  const bool y_full = (by > 0) & (by < IMG / TH - 1);

  // ---- vertical pass: one task per thread, perfectly balanced ----
  vtask(tid, x0, y0, y_full, p1, p2, wv, V);

  __syncthreads();   // the only barrier

  // ---- horizontal pass: 512 of 576 threads, thread = (1 row, 4 output cols).
  // Mapping r = tid&15 + RS=150: every b64 read hits each bank exactly twice
  // (round-5 verified: conflicts 14.8M -> 5.2M). The idle wave sits in the
  // SHORT phase only.
  if (tid < 512) {
    const int r  = tid & 15;           // row 0..15
    const int c4 = (tid >> 4) << 2;    // output col offset 0..124

    float acc[4][4];
    #pragma unroll
    for (int f = 0; f < 4; ++f)
      #pragma unroll
      for (int c = 0; c < 4; ++c) acc[f][c] = 0.f;

    float v[16];   // function scope, constant indices only (SROA-safe)
    #pragma unroll
    for (int f = 0; f < 4; ++f) {
      // window: intermediate local cols c4+2 .. c4+17; taps use c4+3 .. c4+16
      const float* row = &V[f][r][c4 + 2];
      float2 g0 = *(const float2*)(row + 0);
      float2 g1 = *(const float2*)(row + 2);
      float2 g2 = *(const float2*)(row + 4);
      float2 g3 = *(const float2*)(row + 6);
      float2 g4 = *(const float2*)(row + 8);
      float2 g5 = *(const float2*)(row + 10);
      float2 g6 = *(const float2*)(row + 12);
      float2 g7 = *(const float2*)(row + 14);
      v[0]  = g0.x; v[1]  = g0.y; v[2]  = g1.x; v[3]  = g1.y;
      v[4]  = g2.x; v[5]  = g2.y; v[6]  = g3.x; v[7]  = g3.y;
      v[8]  = g4.x; v[9]  = g4.y; v[10] = g5.x; v[11] = g5.y;
      v[12] = g6.x; v[13] = g6.y; v[14] = g7.x; v[15] = g7.y;
      // output col c taps v[c+1+k], k=0..10  (v[i] = local col c4+2+i)
      #pragma unroll
      for (int k = 0; k < 11; ++k) {
        float wk = wv.w[k];
        #pragma unroll
        for (int c = 0; c < 4; ++c) acc[f][c] += wk * v[c + 1 + k];
      }
    }

    float res[4];
    #pragma unroll
    for (int c = 0; c < 4; ++c) {
      float mu1 = acc[0][c], mu2 = acc[1][c];
      float mu1s = mu1 * mu1, mu2s = mu2 * mu2, mu12 = mu1 * mu2;
      float sS  = acc[2][c] - mu1s - mu2s;   // sigma1_sq + sigma2_sq
      float s12 = acc[3][c] - mu12;
      float num = (2.f * mu12 + C1) * (2.f * s12 + C2);
      float den = (mu1s + mu2s + C1) * (sS + C2);
      res[c] = num / den;
    }
    float* op = out + (size_t)n * IMG * IMG + (size_t)(y0 + r) * IMG + x0 + c4;
    *(float4*)op = make_float4(res[0], res[1], res[2], res[3]);
  }
}

extern "C" void kernel_launch(void* const* d_in, const int* in_sizes, int n_in,
                              void* d_out, int out_size, void* d_ws, size_t ws_size,
                              hipStream_t stream) {
  const float* img1 = (const float*)d_in[0];
  const float* img2 = (const float*)d_in[1];
  float* out = (float*)d_out;
  unsigned* ws = (unsigned*)d_ws;          // [0..1]: final max/min; [16..]: partials
  unsigned* part = ws + 16;
  int n = in_sizes[0];             // 32*1*512*512
  int batch = n / (IMG * IMG);     // 32

  // Gaussian window, center at ws/2 = 5.5 (asymmetric!), normalized
  W11 wv;
  double g[11], s = 0.0;
  for (int i = 0; i < 11; ++i) { double d = i - 5.5; g[i] = exp(-(d * d) / 4.5); s += g[i]; }
  for (int i = 0; i < 11; ++i) wv.w[i] = (float)(g[i] / s);

  minmax_part<<<MMB, 256, 0, stream>>>((const float4*)img1, n / 4, part);
  minmax_final<<<1, 256, 0, stream>>>(part, ws);
  dim3 grid(IMG / TW, IMG / TH, batch);
  ssim_k<<<grid, BT, 0, stream>>>(img1, img2, out, ws, wv);
}

// Round 8
// 136.423 us; speedup vs baseline: 1.2045x; 1.2045x over previous
//
#include <hip/hip_runtime.h>
#include <math.h>

#define IMG 512
#define TW 128     // output tile width
#define TH 16      // output tile height
#define RS 150     // LDS row stride floats: 150%32=22, gcd(22,32)=2 -> 16 rows cover all
                   // 16 even bank residues exactly once (h-read conflict killer, round 5)
#define NQ 36      // col-quads per intermediate row (cols x0-8 .. x0+135; halo = 2 full quads/side)
#define NV2 (8 * NQ)   // 288 two-row vertical tasks
#define MMB 1024   // minmax stage-1 blocks

struct W11 { float w[11]; };

__device__ __forceinline__ unsigned omap(float f) {
  unsigned b = __float_as_uint(f);
  return (b & 0x80000000u) ? ~b : (b | 0x80000000u);
}
__device__ __forceinline__ float ounmap(unsigned u) {
  return __uint_as_float((u & 0x80000000u) ? (u ^ 0x80000000u) : ~u);
}

// Stage 1: per-block partial min/max -> disjoint slots, no atomics.
__global__ __launch_bounds__(256) void minmax_part(const float4* __restrict__ img,
                                                   int n4, unsigned* __restrict__ part) {
  unsigned mx = 0u, mn = 0xFFFFFFFFu;
  int stride = gridDim.x * blockDim.x;
  for (int i = blockIdx.x * blockDim.x + threadIdx.x; i < n4; i += stride) {
    float4 v = img[i];
    unsigned a = omap(v.x), b = omap(v.y), c = omap(v.z), d = omap(v.w);
    mx = max(mx, max(max(a, b), max(c, d)));
    mn = min(mn, min(min(a, b), min(c, d)));
  }
  #pragma unroll
  for (int off = 32; off > 0; off >>= 1) {
    mx = max(mx, __shfl_down(mx, off));
    mn = min(mn, __shfl_down(mn, off));
  }
  __shared__ unsigned smx[4], smn[4];
  int lane = threadIdx.x & 63, wv = threadIdx.x >> 6;
  if (lane == 0) { smx[wv] = mx; smn[wv] = mn; }
  __syncthreads();
  if (threadIdx.x == 0) {
    mx = max(max(smx[0], smx[1]), max(smx[2], smx[3]));
    mn = min(min(smn[0], smn[1]), min(smn[2], smn[3]));
    part[2 * blockIdx.x]     = mx;
    part[2 * blockIdx.x + 1] = mn;
  }
}

// Stage 2: fold MMB partial pairs into ws[0]=max, ws[1]=min.
__global__ __launch_bounds__(256) void minmax_final(const unsigned* __restrict__ part,
                                                    unsigned* __restrict__ ws) {
  unsigned mx = 0u, mn = 0xFFFFFFFFu;
  for (int i = threadIdx.x; i < MMB; i += 256) {
    mx = max(mx, part[2 * i]);
    mn = min(mn, part[2 * i + 1]);
  }
  #pragma unroll
  for (int off = 32; off > 0; off >>= 1) {
    mx = max(mx, __shfl_down(mx, off));
    mn = min(mn, __shfl_down(mn, off));
  }
  __shared__ unsigned smx[4], smn[4];
  int lane = threadIdx.x & 63, wv = threadIdx.x >> 6;
  if (lane == 0) { smx[wv] = mx; smn[wv] = mn; }
  __syncthreads();
  if (threadIdx.x == 0) {
    ws[0] = max(max(smx[0], smx[1]), max(smx[2], smx[3]));
    ws[1] = min(min(smn[0], smn[1]), min(smn[2], smn[3]));
  }
}

// One TWO-ROW vertical task: 11-tap v-conv of {a, b, a^2+b^2, a*b} for rows
// (2p, 2p+1) x 4 cols from 12 loaded rows. Round-8 change: round-6/7 budget
// showed L1 return traffic (each input row re-read ~6.8x by 1-row tasks) was
// the largest per-block consumer; 2-row tasks cut v-phase loads 45% and share
// the square/product math between both output rows (row j=0 takes w[k], row
// j=1 takes w[k-1]; pattern numerically verified in round 2).
__device__ __forceinline__ void vtask2(int t, int x0, int y0, bool y_full,
                                       const float* __restrict__ p1,
                                       const float* __restrict__ p2,
                                       const W11& wv,
                                       float (*V)[TH][RS]) {
  const int p = t / NQ;              // row-pair 0..7
  const int q = t - p * NQ;          // 0..35
  const int gx0 = x0 - 8 + 4 * q;    // multiple of 4; halo quads are fully OOB
  const int gy0 = y0 + 2 * p - 5;    // first of 12 input rows

  // Accumulators: A = row 2p, B = row 2p+1. Arrays with constant indices only
  // after full unroll (SROA-safe; the round-1/3 spills came from punning /
  // doubled live load-streams, not from constant-indexed arrays).
  float A[4][4], B[4][4];
  #pragma unroll
  for (int f = 0; f < 4; ++f)
    #pragma unroll
    for (int c = 0; c < 4; ++c) { A[f][c] = 0.f; B[f][c] = 0.f; }

#define VSTEP2(k, a, b)                                                       \
  {                                                                           \
    float sx = a.x * a.x + b.x * b.x, sy = a.y * a.y + b.y * b.y;             \
    float sz = a.z * a.z + b.z * b.z, sw = a.w * a.w + b.w * b.w;             \
    float px = a.x * b.x, py = a.y * b.y, pz = a.z * b.z, pw = a.w * b.w;     \
    if ((k) < 11) { float w = wv.w[(k)];                                      \
      A[0][0] += w * a.x; A[0][1] += w * a.y; A[0][2] += w * a.z; A[0][3] += w * a.w; \
      A[1][0] += w * b.x; A[1][1] += w * b.y; A[1][2] += w * b.z; A[1][3] += w * b.w; \
      A[2][0] += w * sx;  A[2][1] += w * sy;  A[2][2] += w * sz;  A[2][3] += w * sw;  \
      A[3][0] += w * px;  A[3][1] += w * py;  A[3][2] += w * pz;  A[3][3] += w * pw; }\
    if ((k) > 0) { float w = wv.w[(k) - 1];                                   \
      B[0][0] += w * a.x; B[0][1] += w * a.y; B[0][2] += w * a.z; B[0][3] += w * a.w; \
      B[1][0] += w * b.x; B[1][1] += w * b.y; B[1][2] += w * b.z; B[1][3] += w * b.w; \
      B[2][0] += w * sx;  B[2][1] += w * sy;  B[2][2] += w * sz;  B[2][3] += w * sw;  \
      B[3][0] += w * px;  B[3][1] += w * py;  B[3][2] += w * pz;  B[3][3] += w * pw; }\
  }

  if ((unsigned)gx0 < IMG) {
    if (y_full) {
      const float4* Ap = (const float4*)(p1 + (size_t)gy0 * IMG + gx0);
      const float4* Bp = (const float4*)(p2 + (size_t)gy0 * IMG + gx0);
      #pragma unroll
      for (int k = 0; k < 12; ++k) {
        float4 a = Ap[k * (IMG / 4)];
        float4 b = Bp[k * (IMG / 4)];
        VSTEP2(k, a, b);
      }
    } else {
      #pragma unroll
      for (int k = 0; k < 12; ++k) {
        int row = gy0 + k;
        float4 a = make_float4(0.f, 0.f, 0.f, 0.f);
        float4 b = make_float4(0.f, 0.f, 0.f, 0.f);
        if ((unsigned)row < IMG) {
          a = *(const float4*)(p1 + (size_t)row * IMG + gx0);
          b = *(const float4*)(p2 + (size_t)row * IMG + gx0);
        }
        VSTEP2(k, a, b);
      }
    }
  }
#undef VSTEP2

  // b64 writes, consecutive lanes -> consecutive addresses (clean class).
  const int r0 = 2 * p;
  *(float2*)&V[0][r0][4 * q]         = make_float2(A[0][0], A[0][1]);
  *(float2*)&V[0][r0][4 * q + 2]     = make_float2(A[0][2], A[0][3]);
  *(float2*)&V[1][r0][4 * q]         = make_float2(A[1][0], A[1][1]);
  *(float2*)&V[1][r0][4 * q + 2]     = make_float2(A[1][2], A[1][3]);
  *(float2*)&V[2][r0][4 * q]         = make_float2(A[2][0], A[2][1]);
  *(float2*)&V[2][r0][4 * q + 2]     = make_float2(A[2][2], A[2][3]);
  *(float2*)&V[3][r0][4 * q]         = make_float2(A[3][0], A[3][1]);
  *(float2*)&V[3][r0][4 * q + 2]     = make_float2(A[3][2], A[3][3]);
  *(float2*)&V[0][r0 + 1][4 * q]     = make_float2(B[0][0], B[0][1]);
  *(float2*)&V[0][r0 + 1][4 * q + 2] = make_float2(B[0][2], B[0][3]);
  *(float2*)&V[1][r0 + 1][4 * q]     = make_float2(B[1][0], B[1][1]);
  *(float2*)&V[1][r0 + 1][4 * q + 2] = make_float2(B[1][2], B[1][3]);
  *(float2*)&V[2][r0 + 1][4 * q]     = make_float2(B[2][0], B[2][1]);
  *(float2*)&V[2][r0 + 1][4 * q + 2] = make_float2(B[2][2], B[2][3]);
  *(float2*)&V[3][r0 + 1][4 * q]     = make_float2(B[3][0], B[3][1]);
  *(float2*)&V[3][r0 + 1][4 * q + 2] = make_float2(B[3][2], B[3][3]);
}

// Fused SSIM, v-first, 2-row v-tasks, b64-only LDS, conflict-minimized.
// Shell identical to round 6 (the measured best): 512 threads / 8 waves /
// 38.4 KB LDS -> 4 resident blocks = 32 waves/CU. Round-7 lesson: resident-
// block count dominates intra-block critical path at this operating point --
// v-phase concentrates its 288 tasks on threads 0..287 and lets waves 4.5-8
// park at the barrier (other blocks' waves fill the CU).
// launch_bounds(512,4): 128-VGPR cap, proven spill-free regime.
__global__ __launch_bounds__(512, 4) void ssim_k(const float* __restrict__ img1,
                                                 const float* __restrict__ img2,
                                                 float* __restrict__ out,
                                                 const unsigned* __restrict__ ws,
                                                 W11 wv) {
  __shared__ float V[4][TH][RS];   // 38400 B

  const int tid = threadIdx.x;
  const int bx = blockIdx.x, by = blockIdx.y, n = blockIdx.z;
  const float* p1 = img1 + (size_t)n * IMG * IMG;
  const float* p2 = img2 + (size_t)n * IMG * IMG;
  const int x0 = bx * TW;
  const int y0 = by * TH;

  // C1/C2 (scalar loads issued early; needed after the barrier)
  float L = ounmap(ws[0]) - ounmap(ws[1]);
  if (L == 0.f) L = 5.f;
  float C1 = 0.01f * L; C1 *= C1;
  float C2 = 0.03f * L; C2 *= C2;

  const bool y_full = (by > 0) & (by < IMG / TH - 1);

  // ---- vertical pass: 288 two-row tasks on threads 0..287 ----
  if (tid < NV2) vtask2(tid, x0, y0, y_full, p1, p2, wv, V);

  __syncthreads();   // the only barrier

  // ---- horizontal pass: all 512 threads, thread = (1 row, 4 output cols).
  // Mapping r = tid&15 + RS=150: every b64 read hits each bank at most ~2x
  // (round-5 verified: conflicts 14.8M -> 5.2M).
  {
    const int r  = tid & 15;           // row 0..15
    const int c4 = (tid >> 4) << 2;    // output col offset 0..124

    float acc[4][4];
    #pragma unroll
    for (int f = 0; f < 4; ++f)
      #pragma unroll
      for (int c = 0; c < 4; ++c) acc[f][c] = 0.f;

    float v[16];   // function scope, constant indices only (SROA-safe)
    #pragma unroll
    for (int f = 0; f < 4; ++f) {
      // window: intermediate local cols c4+2 .. c4+17; taps use c4+3 .. c4+16
      const float* row = &V[f][r][c4 + 2];
      float2 g0 = *(const float2*)(row + 0);
      float2 g1 = *(const float2*)(row + 2);
      float2 g2 = *(const float2*)(row + 4);
      float2 g3 = *(const float2*)(row + 6);
      float2 g4 = *(const float2*)(row + 8);
      float2 g5 = *(const float2*)(row + 10);
      float2 g6 = *(const float2*)(row + 12);
      float2 g7 = *(const float2*)(row + 14);
      v[0]  = g0.x; v[1]  = g0.y; v[2]  = g1.x; v[3]  = g1.y;
      v[4]  = g2.x; v[5]  = g2.y; v[6]  = g3.x; v[7]  = g3.y;
      v[8]  = g4.x; v[9]  = g4.y; v[10] = g5.x; v[11] = g5.y;
      v[12] = g6.x; v[13] = g6.y; v[14] = g7.x; v[15] = g7.y;
      // output col c taps v[c+1+k], k=0..10  (v[i] = local col c4+2+i)
      #pragma unroll
      for (int k = 0; k < 11; ++k) {
        float wk = wv.w[k];
        #pragma unroll
        for (int c = 0; c < 4; ++c) acc[f][c] += wk * v[c + 1 + k];
      }
    }

    float res[4];
    #pragma unroll
    for (int c = 0; c < 4; ++c) {
      float mu1 = acc[0][c], mu2 = acc[1][c];
      float mu1s = mu1 * mu1, mu2s = mu2 * mu2, mu12 = mu1 * mu2;
      float sS  = acc[2][c] - mu1s - mu2s;   // sigma1_sq + sigma2_sq
      float s12 = acc[3][c] - mu12;
      float num = (2.f * mu12 + C1) * (2.f * s12 + C2);
      float den = (mu1s + mu2s + C1) * (sS + C2);
      res[c] = num / den;
    }
    float* op = out + (size_t)n * IMG * IMG + (size_t)(y0 + r) * IMG + x0 + c4;
    *(float4*)op = make_float4(res[0], res[1], res[2], res[3]);
  }
}

extern "C" void kernel_launch(void* const* d_in, const int* in_sizes, int n_in,
                              void* d_out, int out_size, void* d_ws, size_t ws_size,
                              hipStream_t stream) {
  const float* img1 = (const float*)d_in[0];
  const float* img2 = (const float*)d_in[1];
  float* out = (float*)d_out;
  unsigned* ws = (unsigned*)d_ws;          // [0..1]: final max/min; [16..]: partials
  unsigned* part = ws + 16;
  int n = in_sizes[0];             // 32*1*512*512
  int batch = n / (IMG * IMG);     // 32

  // Gaussian window, center at ws/2 = 5.5 (asymmetric!), normalized
  W11 wv;
  double g[11], s = 0.0;
  for (int i = 0; i < 11; ++i) { double d = i - 5.5; g[i] = exp(-(d * d) / 4.5); s += g[i]; }
  for (int i = 0; i < 11; ++i) wv.w[i] = (float)(g[i] / s);

  minmax_part<<<MMB, 256, 0, stream>>>((const float4*)img1, n / 4, part);
  minmax_final<<<1, 256, 0, stream>>>(part, ws);
  dim3 grid(IMG / TW, IMG / TH, batch);
  ssim_k<<<grid, 512, 0, stream>>>(img1, img2, out, ws, wv);
}

// Round 9
// 132.936 us; speedup vs baseline: 1.2361x; 1.0262x over previous
//
#include <hip/hip_runtime.h>
#include <math.h>

#define IMG 512
#define TW 64      // output tile width (round-9: halved to double resident blocks/CU)
#define TH 16      // output tile height
#define RS 82      // LDS row stride floats: 82%32=18, gcd(18,32)=2 -> 16 row bases cover
                   // all 16 even bank residues exactly once (min-conflict h-reads)
#define NQ 20      // col-quads per intermediate row (cols x0-8 .. x0+71; halo = 2 quads/side)
#define NV2 (8 * NQ)   // 160 two-row vertical tasks
#define BT 256     // block threads = 4 waves; LDS 21.0KB -> 7 blocks/CU (28 waves),
                   // 7 independent barrier groups vs round-8's 4 (phase diversity)
#define MMB 1024   // minmax stage-1 blocks

struct W11 { float w[11]; };

__device__ __forceinline__ unsigned omap(float f) {
  unsigned b = __float_as_uint(f);
  return (b & 0x80000000u) ? ~b : (b | 0x80000000u);
}
__device__ __forceinline__ float ounmap(unsigned u) {
  return __uint_as_float((u & 0x80000000u) ? (u ^ 0x80000000u) : ~u);
}

// Stage 1: per-block partial min/max -> disjoint slots, no atomics.
__global__ __launch_bounds__(256) void minmax_part(const float4* __restrict__ img,
                                                   int n4, unsigned* __restrict__ part) {
  unsigned mx = 0u, mn = 0xFFFFFFFFu;
  int stride = gridDim.x * blockDim.x;
  for (int i = blockIdx.x * blockDim.x + threadIdx.x; i < n4; i += stride) {
    float4 v = img[i];
    unsigned a = omap(v.x), b = omap(v.y), c = omap(v.z), d = omap(v.w);
    mx = max(mx, max(max(a, b), max(c, d)));
    mn = min(mn, min(min(a, b), min(c, d)));
  }
  #pragma unroll
  for (int off = 32; off > 0; off >>= 1) {
    mx = max(mx, __shfl_down(mx, off));
    mn = min(mn, __shfl_down(mn, off));
  }
  __shared__ unsigned smx[4], smn[4];
  int lane = threadIdx.x & 63, wv = threadIdx.x >> 6;
  if (lane == 0) { smx[wv] = mx; smn[wv] = mn; }
  __syncthreads();
  if (threadIdx.x == 0) {
    mx = max(max(smx[0], smx[1]), max(smx[2], smx[3]));
    mn = min(min(smn[0], smn[1]), min(smn[2], smn[3]));
    part[2 * blockIdx.x]     = mx;
    part[2 * blockIdx.x + 1] = mn;
  }
}

// Stage 2: fold MMB partial pairs into ws[0]=max, ws[1]=min.
__global__ __launch_bounds__(256) void minmax_final(const unsigned* __restrict__ part,
                                                    unsigned* __restrict__ ws) {
  unsigned mx = 0u, mn = 0xFFFFFFFFu;
  for (int i = threadIdx.x; i < MMB; i += 256) {
    mx = max(mx, part[2 * i]);
    mn = min(mn, part[2 * i + 1]);
  }
  #pragma unroll
  for (int off = 32; off > 0; off >>= 1) {
    mx = max(mx, __shfl_down(mx, off));
    mn = min(mn, __shfl_down(mn, off));
  }
  __shared__ unsigned smx[4], smn[4];
  int lane = threadIdx.x & 63, wv = threadIdx.x >> 6;
  if (lane == 0) { smx[wv] = mx; smn[wv] = mn; }
  __syncthreads();
  if (threadIdx.x == 0) {
    ws[0] = max(max(smx[0], smx[1]), max(smx[2], smx[3]));
    ws[1] = min(min(smn[0], smn[1]), min(smn[2], smn[3]));
  }
}

// One TWO-ROW vertical task: 11-tap v-conv of {a, b, a^2+b^2, a*b} for rows
// (2p, 2p+1) x 4 cols from 12 loaded rows (round-8 win: halves L1 traffic and
// shares square/product math; row j=0 takes w[k], j=1 takes w[k-1]).
__device__ __forceinline__ void vtask2(int t, int x0, int y0, bool y_full,
                                       const float* __restrict__ p1,
                                       const float* __restrict__ p2,
                                       const W11& wv,
                                       float (*V)[TH][RS]) {
  const int p = t / NQ;              // row-pair 0..7
  const int q = t - p * NQ;          // 0..19
  const int gx0 = x0 - 8 + 4 * q;    // multiple of 4; halo quads are fully OOB
  const int gy0 = y0 + 2 * p - 5;    // first of 12 input rows

  float A[4][4], B[4][4];            // constant-indexed after unroll (SROA-safe)
  #pragma unroll
  for (int f = 0; f < 4; ++f)
    #pragma unroll
    for (int c = 0; c < 4; ++c) { A[f][c] = 0.f; B[f][c] = 0.f; }

#define VSTEP2(k, a, b)                                                       \
  {                                                                           \
    float sx = a.x * a.x + b.x * b.x, sy = a.y * a.y + b.y * b.y;             \
    float sz = a.z * a.z + b.z * b.z, sw = a.w * a.w + b.w * b.w;             \
    float px = a.x * b.x, py = a.y * b.y, pz = a.z * b.z, pw = a.w * b.w;     \
    if ((k) < 11) { float w = wv.w[(k)];                                      \
      A[0][0] += w * a.x; A[0][1] += w * a.y; A[0][2] += w * a.z; A[0][3] += w * a.w; \
      A[1][0] += w * b.x; A[1][1] += w * b.y; A[1][2] += w * b.z; A[1][3] += w * b.w; \
      A[2][0] += w * sx;  A[2][1] += w * sy;  A[2][2] += w * sz;  A[2][3] += w * sw;  \
      A[3][0] += w * px;  A[3][1] += w * py;  A[3][2] += w * pz;  A[3][3] += w * pw; }\
    if ((k) > 0) { float w = wv.w[(k) - 1];                                   \
      B[0][0] += w * a.x; B[0][1] += w * a.y; B[0][2] += w * a.z; B[0][3] += w * a.w; \
      B[1][0] += w * b.x; B[1][1] += w * b.y; B[1][2] += w * b.z; B[1][3] += w * b.w; \
      B[2][0] += w * sx;  B[2][1] += w * sy;  B[2][2] += w * sz;  B[2][3] += w * sw;  \
      B[3][0] += w * px;  B[3][1] += w * py;  B[3][2] += w * pz;  B[3][3] += w * pw; }\
  }

  if ((unsigned)gx0 < IMG) {
    if (y_full) {
      const float4* Ap = (const float4*)(p1 + (size_t)gy0 * IMG + gx0);
      const float4* Bp = (const float4*)(p2 + (size_t)gy0 * IMG + gx0);
      #pragma unroll
      for (int k = 0; k < 12; ++k) {
        float4 a = Ap[k * (IMG / 4)];
        float4 b = Bp[k * (IMG / 4)];
        VSTEP2(k, a, b);
      }
    } else {
      #pragma unroll
      for (int k = 0; k < 12; ++k) {
        int row = gy0 + k;
        float4 a = make_float4(0.f, 0.f, 0.f, 0.f);
        float4 b = make_float4(0.f, 0.f, 0.f, 0.f);
        if ((unsigned)row < IMG) {
          a = *(const float4*)(p1 + (size_t)row * IMG + gx0);
          b = *(const float4*)(p2 + (size_t)row * IMG + gx0);
        }
        VSTEP2(k, a, b);
      }
    }
  }
#undef VSTEP2

  // b64 writes, consecutive lanes -> consecutive addresses (clean class).
  const int r0 = 2 * p;
  *(float2*)&V[0][r0][4 * q]         = make_float2(A[0][0], A[0][1]);
  *(float2*)&V[0][r0][4 * q + 2]     = make_float2(A[0][2], A[0][3]);
  *(float2*)&V[1][r0][4 * q]         = make_float2(A[1][0], A[1][1]);
  *(float2*)&V[1][r0][4 * q + 2]     = make_float2(A[1][2], A[1][3]);
  *(float2*)&V[2][r0][4 * q]         = make_float2(A[2][0], A[2][1]);
  *(float2*)&V[2][r0][4 * q + 2]     = make_float2(A[2][2], A[2][3]);
  *(float2*)&V[3][r0][4 * q]         = make_float2(A[3][0], A[3][1]);
  *(float2*)&V[3][r0][4 * q + 2]     = make_float2(A[3][2], A[3][3]);
  *(float2*)&V[0][r0 + 1][4 * q]     = make_float2(B[0][0], B[0][1]);
  *(float2*)&V[0][r0 + 1][4 * q + 2] = make_float2(B[0][2], B[0][3]);
  *(float2*)&V[1][r0 + 1][4 * q]     = make_float2(B[1][0], B[1][1]);
  *(float2*)&V[1][r0 + 1][4 * q + 2] = make_float2(B[1][2], B[1][3]);
  *(float2*)&V[2][r0 + 1][4 * q]     = make_float2(B[2][0], B[2][1]);
  *(float2*)&V[2][r0 + 1][4 * q + 2] = make_float2(B[2][2], B[2][3]);
  *(float2*)&V[3][r0 + 1][4 * q]     = make_float2(B[3][0], B[3][1]);
  *(float2*)&V[3][r0 + 1][4 * q + 2] = make_float2(B[3][2], B[3][3]);
}

// Fused SSIM, v-first, 2-row v-tasks, b64-only LDS.
// Round-9: 256-thread / 21.0KB-LDS blocks -> 7 resident blocks/CU (28 waves in
// 7 independent barrier groups vs round-8's 4 groups of 8 waves). Round-7/8
// lesson: at this latency-bound operating point, resident-block count (phase
// diversity) dominates; smaller barrier groups also shrink the parked-wave
// cost of the concentrated v-phase (160 tasks on threads 0..159).
// launch_bounds(256,4): 128-VGPR cap, proven spill-free regime (compiler
// consistently lands at 64 VGPR = full 8 waves/SIMD eligibility).
__global__ __launch_bounds__(BT, 4) void ssim_k(const float* __restrict__ img1,
                                                const float* __restrict__ img2,
                                                float* __restrict__ out,
                                                const unsigned* __restrict__ ws,
                                                W11 wv) {
  __shared__ float V[4][TH][RS];   // 20992 B

  const int tid = threadIdx.x;
  const int bx = blockIdx.x, by = blockIdx.y, n = blockIdx.z;
  const float* p1 = img1 + (size_t)n * IMG * IMG;
  const float* p2 = img2 + (size_t)n * IMG * IMG;
  const int x0 = bx * TW;
  const int y0 = by * TH;

  // C1/C2 (scalar loads issued early; needed after the barrier)
  float L = ounmap(ws[0]) - ounmap(ws[1]);
  if (L == 0.f) L = 5.f;
  float C1 = 0.01f * L; C1 *= C1;
  float C2 = 0.03f * L; C2 *= C2;

  const bool y_full = (by > 0) & (by < IMG / TH - 1);

  // ---- vertical pass: 160 two-row tasks on threads 0..159 ----
  if (tid < NV2) vtask2(tid, x0, y0, y_full, p1, p2, wv, V);

  __syncthreads();   // the only barrier

  // ---- horizontal pass: all 256 threads, thread = (1 row, 4 output cols).
  // Bank check (RS=82): 32-lane phase = 16 rows x 2 col-groups; 18r mod 32
  // covers all 16 even residues once, +4h shifts -> every even start-residue
  // hit exactly twice = 2 lanes/bank = wave64-b64 minimum.
  {
    const int r  = tid & 15;           // row 0..15
    const int c4 = (tid >> 4) << 2;    // output col offset 0..60

    float acc[4][4];
    #pragma unroll
    for (int f = 0; f < 4; ++f)
      #pragma unroll
      for (int c = 0; c < 4; ++c) acc[f][c] = 0.f;

    float v[16];   // function scope, constant indices only (SROA-safe)
    #pragma unroll
    for (int f = 0; f < 4; ++f) {
      // window: intermediate local cols c4+2 .. c4+17; taps use c4+3 .. c4+16
      const float* row = &V[f][r][c4 + 2];
      float2 g0 = *(const float2*)(row + 0);
      float2 g1 = *(const float2*)(row + 2);
      float2 g2 = *(const float2*)(row + 4);
      float2 g3 = *(const float2*)(row + 6);
      float2 g4 = *(const float2*)(row + 8);
      float2 g5 = *(const float2*)(row + 10);
      float2 g6 = *(const float2*)(row + 12);
      float2 g7 = *(const float2*)(row + 14);
      v[0]  = g0.x; v[1]  = g0.y; v[2]  = g1.x; v[3]  = g1.y;
      v[4]  = g2.x; v[5]  = g2.y; v[6]  = g3.x; v[7]  = g3.y;
      v[8]  = g4.x; v[9]  = g4.y; v[10] = g5.x; v[11] = g5.y;
      v[12] = g6.x; v[13] = g6.y; v[14] = g7.x; v[15] = g7.y;
      // output col c taps v[c+1+k], k=0..10  (v[i] = local col c4+2+i)
      #pragma unroll
      for (int k = 0; k < 11; ++k) {
        float wk = wv.w[k];
        #pragma unroll
        for (int c = 0; c < 4; ++c) acc[f][c] += wk * v[c + 1 + k];
      }
    }

    float res[4];
    #pragma unroll
    for (int c = 0; c < 4; ++c) {
      float mu1 = acc[0][c], mu2 = acc[1][c];
      float mu1s = mu1 * mu1, mu2s = mu2 * mu2, mu12 = mu1 * mu2;
      float sS  = acc[2][c] - mu1s - mu2s;   // sigma1_sq + sigma2_sq
      float s12 = acc[3][c] - mu12;
      float num = (2.f * mu12 + C1) * (2.f * s12 + C2);
      float den = (mu1s + mu2s + C1) * (sS + C2);
      res[c] = num / den;
    }
    float* op = out + (size_t)n * IMG * IMG + (size_t)(y0 + r) * IMG + x0 + c4;
    *(float4*)op = make_float4(res[0], res[1], res[2], res[3]);
  }
}

extern "C" void kernel_launch(void* const* d_in, const int* in_sizes, int n_in,
                              void* d_out, int out_size, void* d_ws, size_t ws_size,
                              hipStream_t stream) {
  const float* img1 = (const float*)d_in[0];
  const float* img2 = (const float*)d_in[1];
  float* out = (float*)d_out;
  unsigned* ws = (unsigned*)d_ws;          // [0..1]: final max/min; [16..]: partials
  unsigned* part = ws + 16;
  int n = in_sizes[0];             // 32*1*512*512
  int batch = n / (IMG * IMG);     // 32

  // Gaussian window, center at ws/2 = 5.5 (asymmetric!), normalized
  W11 wv;
  double g[11], s = 0.0;
  for (int i = 0; i < 11; ++i) { double d = i - 5.5; g[i] = exp(-(d * d) / 4.5); s += g[i]; }
  for (int i = 0; i < 11; ++i) wv.w[i] = (float)(g[i] / s);

  minmax_part<<<MMB, 256, 0, stream>>>((const float4*)img1, n / 4, part);
  minmax_final<<<1, 256, 0, stream>>>(part, ws);
  dim3 grid(IMG / TW, IMG / TH, batch);
  ssim_k<<<grid, BT, 0, stream>>>(img1, img2, out, ws, wv);
}

// Round 10
// 132.846 us; speedup vs baseline: 1.2370x; 1.0007x over previous
//
#include <hip/hip_runtime.h>
#include <math.h>

#define IMG 512
#define TW 64      // output tile width
#define TH 16      // output tile height (4 rows per wave x 4 waves)
#define RS 82      // LDS row stride floats: 82%32=18, gcd(18,32)=2 -> row bases cover
                   // all 16 even bank residues (min-conflict h-reads, round 5/9)
#define NQ 20      // col-quads per intermediate row (cols x0-8 .. x0+71; halo = 2 quads/side)
#define BT 256     // 4 waves; LDS 21.0KB -> 7 blocks/CU = 28 fully independent waves
#define MMB 1024   // minmax stage-1 blocks

struct W11 { float w[11]; };

__device__ __forceinline__ unsigned omap(float f) {
  unsigned b = __float_as_uint(f);
  return (b & 0x80000000u) ? ~b : (b | 0x80000000u);
}
__device__ __forceinline__ float ounmap(unsigned u) {
  return __uint_as_float((u & 0x80000000u) ? (u ^ 0x80000000u) : ~u);
}

// Stage 1: per-block partial min/max -> disjoint slots, no atomics.
__global__ __launch_bounds__(256) void minmax_part(const float4* __restrict__ img,
                                                   int n4, unsigned* __restrict__ part) {
  unsigned mx = 0u, mn = 0xFFFFFFFFu;
  int stride = gridDim.x * blockDim.x;
  for (int i = blockIdx.x * blockDim.x + threadIdx.x; i < n4; i += stride) {
    float4 v = img[i];
    unsigned a = omap(v.x), b = omap(v.y), c = omap(v.z), d = omap(v.w);
    mx = max(mx, max(max(a, b), max(c, d)));
    mn = min(mn, min(min(a, b), min(c, d)));
  }
  #pragma unroll
  for (int off = 32; off > 0; off >>= 1) {
    mx = max(mx, __shfl_down(mx, off));
    mn = min(mn, __shfl_down(mn, off));
  }
  __shared__ unsigned smx[4], smn[4];
  int lane = threadIdx.x & 63, wv = threadIdx.x >> 6;
  if (lane == 0) { smx[wv] = mx; smn[wv] = mn; }
  __syncthreads();
  if (threadIdx.x == 0) {
    mx = max(max(smx[0], smx[1]), max(smx[2], smx[3]));
    mn = min(min(smn[0], smn[1]), min(smn[2], smn[3]));
    part[2 * blockIdx.x]     = mx;
    part[2 * blockIdx.x + 1] = mn;
  }
}

// Stage 2: fold MMB partial pairs into ws[0]=max, ws[1]=min.
__global__ __launch_bounds__(256) void minmax_final(const unsigned* __restrict__ part,
                                                    unsigned* __restrict__ ws) {
  unsigned mx = 0u, mn = 0xFFFFFFFFu;
  for (int i = threadIdx.x; i < MMB; i += 256) {
    mx = max(mx, part[2 * i]);
    mn = min(mn, part[2 * i + 1]);
  }
  #pragma unroll
  for (int off = 32; off > 0; off >>= 1) {
    mx = max(mx, __shfl_down(mx, off));
    mn = min(mn, __shfl_down(mn, off));
  }
  __shared__ unsigned smx[4], smn[4];
  int lane = threadIdx.x & 63, wv = threadIdx.x >> 6;
  if (lane == 0) { smx[wv] = mx; smn[wv] = mn; }
  __syncthreads();
  if (threadIdx.x == 0) {
    ws[0] = max(max(smx[0], smx[1]), max(smx[2], smx[3]));
    ws[1] = min(min(smn[0], smn[1]), min(smn[2], smn[3]));
  }
}

// One TWO-ROW vertical task for explicit base row r0: 11-tap v-conv of
// {a, b, a^2+b^2, a*b} for rows (r0, r0+1) x 4 cols from 12 loaded rows
// (round-8 win: halves L1 traffic, shares square/product math; row j=0 takes
// w[k], j=1 takes w[k-1] -- numerically verified round 2).
__device__ __forceinline__ void vtask2w(int r0, int q, int x0, int y0, bool y_full,
                                        const float* __restrict__ p1,
                                        const float* __restrict__ p2,
                                        const W11& wv,
                                        float (*V)[TH][RS]) {
  const int gx0 = x0 - 8 + 4 * q;    // multiple of 4; halo quads are fully OOB
  const int gy0 = y0 + r0 - 5;       // first of 12 input rows

  float A[4][4], B[4][4];            // constant-indexed after unroll (SROA-safe)
  #pragma unroll
  for (int f = 0; f < 4; ++f)
    #pragma unroll
    for (int c = 0; c < 4; ++c) { A[f][c] = 0.f; B[f][c] = 0.f; }

#define VSTEP2(k, a, b)                                                       \
  {                                                                           \
    float sx = a.x * a.x + b.x * b.x, sy = a.y * a.y + b.y * b.y;             \
    float sz = a.z * a.z + b.z * b.z, sw = a.w * a.w + b.w * b.w;             \
    float px = a.x * b.x, py = a.y * b.y, pz = a.z * b.z, pw = a.w * b.w;     \
    if ((k) < 11) { float w = wv.w[(k)];                                      \
      A[0][0] += w * a.x; A[0][1] += w * a.y; A[0][2] += w * a.z; A[0][3] += w * a.w; \
      A[1][0] += w * b.x; A[1][1] += w * b.y; A[1][2] += w * b.z; A[1][3] += w * b.w; \
      A[2][0] += w * sx;  A[2][1] += w * sy;  A[2][2] += w * sz;  A[2][3] += w * sw;  \
      A[3][0] += w * px;  A[3][1] += w * py;  A[3][2] += w * pz;  A[3][3] += w * pw; }\
    if ((k) > 0) { float w = wv.w[(k) - 1];                                   \
      B[0][0] += w * a.x; B[0][1] += w * a.y; B[0][2] += w * a.z; B[0][3] += w * a.w; \
      B[1][0] += w * b.x; B[1][1] += w * b.y; B[1][2] += w * b.z; B[1][3] += w * b.w; \
      B[2][0] += w * sx;  B[2][1] += w * sy;  B[2][2] += w * sz;  B[2][3] += w * sw;  \
      B[3][0] += w * px;  B[3][1] += w * py;  B[3][2] += w * pz;  B[3][3] += w * pw; }\
  }

  if ((unsigned)gx0 < IMG) {
    if (y_full) {
      const float4* Ap = (const float4*)(p1 + (size_t)gy0 * IMG + gx0);
      const float4* Bp = (const float4*)(p2 + (size_t)gy0 * IMG + gx0);
      #pragma unroll
      for (int k = 0; k < 12; ++k) {
        float4 a = Ap[k * (IMG / 4)];
        float4 b = Bp[k * (IMG / 4)];
        VSTEP2(k, a, b);
      }
    } else {
      #pragma unroll
      for (int k = 0; k < 12; ++k) {
        int row = gy0 + k;
        float4 a = make_float4(0.f, 0.f, 0.f, 0.f);
        float4 b = make_float4(0.f, 0.f, 0.f, 0.f);
        if ((unsigned)row < IMG) {
          a = *(const float4*)(p1 + (size_t)row * IMG + gx0);
          b = *(const float4*)(p2 + (size_t)row * IMG + gx0);
        }
        VSTEP2(k, a, b);
      }
    }
  }
#undef VSTEP2

  // b64 writes, consecutive lanes -> consecutive addresses (clean class).
  *(float2*)&V[0][r0][4 * q]         = make_float2(A[0][0], A[0][1]);
  *(float2*)&V[0][r0][4 * q + 2]     = make_float2(A[0][2], A[0][3]);
  *(float2*)&V[1][r0][4 * q]         = make_float2(A[1][0], A[1][1]);
  *(float2*)&V[1][r0][4 * q + 2]     = make_float2(A[1][2], A[1][3]);
  *(float2*)&V[2][r0][4 * q]         = make_float2(A[2][0], A[2][1]);
  *(float2*)&V[2][r0][4 * q + 2]     = make_float2(A[2][2], A[2][3]);
  *(float2*)&V[3][r0][4 * q]         = make_float2(A[3][0], A[3][1]);
  *(float2*)&V[3][r0][4 * q + 2]     = make_float2(A[3][2], A[3][3]);
  *(float2*)&V[0][r0 + 1][4 * q]     = make_float2(B[0][0], B[0][1]);
  *(float2*)&V[0][r0 + 1][4 * q + 2] = make_float2(B[0][2], B[0][3]);
  *(float2*)&V[1][r0 + 1][4 * q]     = make_float2(B[1][0], B[1][1]);
  *(float2*)&V[1][r0 + 1][4 * q + 2] = make_float2(B[1][2], B[1][3]);
  *(float2*)&V[2][r0 + 1][4 * q]     = make_float2(B[2][0], B[2][1]);
  *(float2*)&V[2][r0 + 1][4 * q + 2] = make_float2(B[2][2], B[2][3]);
  *(float2*)&V[3][r0 + 1][4 * q]     = make_float2(B[3][0], B[3][1]);
  *(float2*)&V[3][r0 + 1][4 * q + 2] = make_float2(B[3][2], B[3][3]);
}

// Fused SSIM, v-first, WAVE-INDEPENDENT tiles (round-10): both conv passes are
// row-local, so each wave owns 4 output rows end-to-end (v: 2 row-pair tasks x
// 20 quads on its lanes; h: 4 rows x 16 col-groups on all 64 lanes). LDS rows
// are disjoint per wave -> __syncthreads() replaced by an intra-wave fence
// (s_waitcnt lgkmcnt(0) with "memory" clobber + sched_barrier + wave_barrier).
// No wave ever parks on another wave's progress: 28 independent pipelines/CU
// (rounds 7-9 showed barrier groups were the binding constraint; this removes
// the barrier entirely).
__global__ __launch_bounds__(BT, 4) void ssim_k(const float* __restrict__ img1,
                                                const float* __restrict__ img2,
                                                float* __restrict__ out,
                                                const unsigned* __restrict__ ws,
                                                W11 wv) {
  __shared__ float V[4][TH][RS];   // 20992 B -> 7 blocks/CU

  const int tid  = threadIdx.x;
  const int wid  = tid >> 6;       // wave 0..3 owns rows 4*wid .. 4*wid+3
  const int lane = tid & 63;
  const int bx = blockIdx.x, by = blockIdx.y, n = blockIdx.z;
  const float* p1 = img1 + (size_t)n * IMG * IMG;
  const float* p2 = img2 + (size_t)n * IMG * IMG;
  const int x0 = bx * TW;
  const int y0 = by * TH;

  // C1/C2 (scalar loads issued early; needed in the epilogue)
  float L = ounmap(ws[0]) - ounmap(ws[1]);
  if (L == 0.f) L = 5.f;
  float C1 = 0.01f * L; C1 *= C1;
  float C2 = 0.03f * L; C2 *= C2;

  const bool y_full = (by > 0) & (by < IMG / TH - 1);

  // ---- vertical pass: 40 two-row tasks on lanes 0..39 of EACH wave ----
  if (lane < 40) {
    const int p = (lane >= 20) ? 1 : 0;   // row-pair within this wave's rows
    const int q = lane - 20 * p;          // col-quad 0..19
    vtask2w(4 * wid + 2 * p, q, x0, y0, y_full, p1, p2, wv, V);
  }

  // ---- intra-wave fence (replaces __syncthreads): this wave's ds_writes
  // drain before its ds_reads; "memory" clobber orders all LDS ops across the
  // asm; sched_barrier pins the scheduler; wave_barrier is the compiler fence.
  asm volatile("s_waitcnt lgkmcnt(0)" ::: "memory");
  __builtin_amdgcn_sched_barrier(0);
  __builtin_amdgcn_wave_barrier();

  // ---- horizontal pass: all 64 lanes, lane = (own row 4*wid + (lane>>4),
  // 4 output cols). Bank check (RS=82): per 32-lane phase, residues 18r+4c+2
  // cover all 16 even bank residues exactly twice -> b64 minimum (2 lanes/bank).
  {
    const int r  = 4 * wid + (lane >> 4);  // this wave's row
    const int c4 = (lane & 15) << 2;       // output col offset 0..60

    float acc[4][4];
    #pragma unroll
    for (int f = 0; f < 4; ++f)
      #pragma unroll
      for (int c = 0; c < 4; ++c) acc[f][c] = 0.f;

    float v[16];   // function scope, constant indices only (SROA-safe)
    #pragma unroll
    for (int f = 0; f < 4; ++f) {
      // window: intermediate local cols c4+2 .. c4+17; taps use c4+3 .. c4+16
      const float* row = &V[f][r][c4 + 2];
      float2 g0 = *(const float2*)(row + 0);
      float2 g1 = *(const float2*)(row + 2);
      float2 g2 = *(const float2*)(row + 4);
      float2 g3 = *(const float2*)(row + 6);
      float2 g4 = *(const float2*)(row + 8);
      float2 g5 = *(const float2*)(row + 10);
      float2 g6 = *(const float2*)(row + 12);
      float2 g7 = *(const float2*)(row + 14);
      v[0]  = g0.x; v[1]  = g0.y; v[2]  = g1.x; v[3]  = g1.y;
      v[4]  = g2.x; v[5]  = g2.y; v[6]  = g3.x; v[7]  = g3.y;
      v[8]  = g4.x; v[9]  = g4.y; v[10] = g5.x; v[11] = g5.y;
      v[12] = g6.x; v[13] = g6.y; v[14] = g7.x; v[15] = g7.y;
      // output col c taps v[c+1+k], k=0..10  (v[i] = local col c4+2+i)
      #pragma unroll
      for (int k = 0; k < 11; ++k) {
        float wk = wv.w[k];
        #pragma unroll
        for (int c = 0; c < 4; ++c) acc[f][c] += wk * v[c + 1 + k];
      }
    }

    float res[4];
    #pragma unroll
    for (int c = 0; c < 4; ++c) {
      float mu1 = acc[0][c], mu2 = acc[1][c];
      float mu1s = mu1 * mu1, mu2s = mu2 * mu2, mu12 = mu1 * mu2;
      float sS  = acc[2][c] - mu1s - mu2s;   // sigma1_sq + sigma2_sq
      float s12 = acc[3][c] - mu12;
      float num = (2.f * mu12 + C1) * (2.f * s12 + C2);
      float den = (mu1s + mu2s + C1) * (sS + C2);
      res[c] = num / den;
    }
    float* op = out + (size_t)n * IMG * IMG + (size_t)(y0 + r) * IMG + x0 + c4;
    *(float4*)op = make_float4(res[0], res[1], res[2], res[3]);
  }
}

extern "C" void kernel_launch(void* const* d_in, const int* in_sizes, int n_in,
                              void* d_out, int out_size, void* d_ws, size_t ws_size,
                              hipStream_t stream) {
  const float* img1 = (const float*)d_in[0];
  const float* img2 = (const float*)d_in[1];
  float* out = (float*)d_out;
  unsigned* ws = (unsigned*)d_ws;          // [0..1]: final max/min; [16..]: partials
  unsigned* part = ws + 16;
  int n = in_sizes[0];             // 32*1*512*512
  int batch = n / (IMG * IMG);     // 32

  // Gaussian window, center at ws/2 = 5.5 (asymmetric!), normalized
  W11 wv;
  double g[11], s = 0.0;
  for (int i = 0; i < 11; ++i) { double d = i - 5.5; g[i] = exp(-(d * d) / 4.5); s += g[i]; }
  for (int i = 0; i < 11; ++i) wv.w[i] = (float)(g[i] / s);

  minmax_part<<<MMB, 256, 0, stream>>>((const float4*)img1, n / 4, part);
  minmax_final<<<1, 256, 0, stream>>>(part, ws);
  dim3 grid(IMG / TW, IMG / TH, batch);
  ssim_k<<<grid, BT, 0, stream>>>(img1, img2, out, ws, wv);
}